// Round 8
// baseline (2443.548 us; speedup 1.0000x reference)
//
#include <hip/hip_runtime.h>
#include <hip/hip_fp16.h>

typedef _Float16 f16;
typedef _Float16 f16x2 __attribute__((ext_vector_type(2)));
typedef _Float16 f16x8 __attribute__((ext_vector_type(8)));
typedef float    f32x4 __attribute__((ext_vector_type(4)));
typedef unsigned int u32;
typedef unsigned long long u64;

#define BN_EPS 1e-5f

static constexpr int BB  = 32;    // batch
static constexpr int CC  = 128;   // channels
static constexpr int HWN = 1024;  // H*W = L
static constexpr int RIN = 256;
static constexpr int RH  = 512;
static constexpr int OCN = 128;

// ---------------------------------------------------------------- BN stats
__global__ void bn_stats_kernel(const float* __restrict__ x,
                                const float* __restrict__ gamma,
                                const float* __restrict__ beta,
                                float* __restrict__ scale,
                                float* __restrict__ shift) {
    int c = blockIdx.x;
    int tid = threadIdx.x;
    float s = 0.f, s2 = 0.f;
    const float* xc = x + (size_t)c * HWN;
    for (int idx = tid; idx < BB * HWN; idx += 256) {
        int b = idx >> 10, hw = idx & 1023;
        float v = xc[(size_t)b * (CC * HWN) + hw];
        s += v; s2 += v * v;
    }
    for (int off = 32; off > 0; off >>= 1) {
        s  += __shfl_down(s, off, 64);
        s2 += __shfl_down(s2, off, 64);
    }
    __shared__ float ls[4], ls2[4];
    int wv = tid >> 6, ln = tid & 63;
    if (ln == 0) { ls[wv] = s; ls2[wv] = s2; }
    __syncthreads();
    if (tid == 0) {
        float ts  = ls[0] + ls[1] + ls[2] + ls[3];
        float ts2 = ls2[0] + ls2[1] + ls2[2] + ls2[3];
        const float inv_n = 1.0f / (BB * HWN);
        float mean = ts * inv_n;
        float var  = ts2 * inv_n - mean * mean;
        float rstd = rsqrtf(var + BN_EPS);
        float sc = gamma[c] * rstd;
        scale[c] = sc;
        shift[c] = beta[c] - mean * sc;
    }
}

// ------------------------------------------- normalize + transpose -> A1 f16
__global__ void prep_x_kernel(const float* __restrict__ x,
                              const float* __restrict__ scale,
                              const float* __restrict__ shift,
                              f16* __restrict__ A1) {
    __shared__ float tile[32][33];
    int tx = threadIdx.x, ty = threadIdx.y;  // 32 x 8
    int hb = blockIdx.x, cb = blockIdx.y, b = blockIdx.z;
    #pragma unroll
    for (int k = 0; k < 4; k++) {
        int c  = cb * 32 + ty + 8 * k;
        int hw = hb * 32 + tx;
        tile[ty + 8 * k][tx] = x[(size_t)b * (CC * HWN) + (size_t)c * HWN + hw];
    }
    __syncthreads();
    #pragma unroll
    for (int k = 0; k < 4; k++) {
        int hw = hb * 32 + ty + 8 * k;
        int c  = cb * 32 + tx;
        float v = tile[tx][ty + 8 * k];
        A1[(size_t)(b * HWN + hw) * CC + c] = (f16)(v * scale[c] + shift[c]);
    }
}

// ------------------------------------------------------------ weight prep
// wr packing for the (row, k-quarter) RNN layout: thread t of slice s owns
// row j = 128s + (t>>2), k-quarter (t&3) -> 64 h-pairs i2 = (t&3)*64 + k.
__global__ void prep_w_kernel(const float* __restrict__ w_in,
                              const float* __restrict__ w_ih,
                              const float* __restrict__ w_out,
                              const float* __restrict__ w_hh,
                              const float* __restrict__ b_ih,
                              const float* __restrict__ b_hh,
                              f16* __restrict__ w_in_h,
                              f16* __restrict__ w_ih_h,
                              f16* __restrict__ w_out_h,
                              u32* __restrict__ wr,
                              float* __restrict__ bihh,
                              u64* __restrict__ comm) {
    int idx = blockIdx.x * 256 + threadIdx.x;
    if (idx < 32768) { w_in_h[idx] = (f16)w_in[idx]; return; }
    idx -= 32768;
    if (idx < 131072) { w_ih_h[idx] = (f16)w_ih[idx]; return; }
    idx -= 131072;
    if (idx < 65536) { w_out_h[idx] = (f16)w_out[idx]; return; }
    idx -= 65536;
    if (idx < 131072) {
        int s = idx >> 15, rem = idx & 32767;
        int t = rem >> 6, k = rem & 63;
        int j  = s * 128 + (t >> 2);
        int i2 = (t & 3) * 64 + k;
        f16 lo = (f16)w_hh[(size_t)j * 512 + 2 * i2];
        f16 hi = (f16)w_hh[(size_t)j * 512 + 2 * i2 + 1];
        wr[idx] = (u32)__builtin_bit_cast(unsigned short, lo) |
                  ((u32)__builtin_bit_cast(unsigned short, hi) << 16);
        return;
    }
    idx -= 131072;
    if (idx < 512) { bihh[idx] = b_ih[idx] + b_hh[idx]; return; }
    idx -= 512;
    if (idx < 32768) comm[idx] = 0ULL;   // zero BOTH slow (16K) and fast (16K)
}

// ------------------------------------------------------------- MFMA GEMM
template <int MODE>
__global__ void gemm_kernel(const f16* __restrict__ A,
                            const f16* __restrict__ W,
                            const float* __restrict__ bias,
                            void* __restrict__ outp,
                            int N, int K) {
    int wave = threadIdx.x >> 6;
    int lane = threadIdx.x & 63;
    int q = lane >> 4, r = lane & 15;
    int bm = blockIdx.x * 256 + wave * 64;
    int bn = blockIdx.y * 64;

    f32x4 acc[4][4];
    #pragma unroll
    for (int i = 0; i < 4; i++)
        #pragma unroll
        for (int j = 0; j < 4; j++)
            acc[i][j] = (f32x4){0.f, 0.f, 0.f, 0.f};

    const f16* Ap = A + (size_t)(bm + r) * K + 8 * q;
    const f16* Wp = W + (size_t)(bn + r) * K + 8 * q;

    for (int k = 0; k < K; k += 32) {
        f16x8 av[4], bv[4];
        #pragma unroll
        for (int i = 0; i < 4; i++)
            av[i] = *(const f16x8*)(Ap + (size_t)(16 * i) * K + k);
        #pragma unroll
        for (int i = 0; i < 4; i++)
            bv[i] = *(const f16x8*)(Wp + (size_t)(16 * i) * K + k);
        #pragma unroll
        for (int mi = 0; mi < 4; mi++)
            #pragma unroll
            for (int ni = 0; ni < 4; ni++)
                acc[mi][ni] = __builtin_amdgcn_mfma_f32_16x16x32_f16(
                    av[mi], bv[ni], acc[mi][ni], 0, 0, 0);
    }

    #pragma unroll
    for (int mi = 0; mi < 4; mi++) {
        #pragma unroll
        for (int ni = 0; ni < 4; ni++) {
            int col = bn + 16 * ni + r;
            float bval = bias[col];
            #pragma unroll
            for (int i = 0; i < 4; i++) {
                int row = bm + 16 * mi + 4 * q + i;
                float val = acc[mi][ni][i] + bval;
                if (MODE == 0) {
                    val = val - tanhf(val);
                    ((f16*)outp)[(size_t)row * N + col] = (f16)val;
                } else if (MODE == 1) {
                    ((f16*)outp)[(size_t)row * N + col] = (f16)val;
                } else {
                    int b = row >> 10, hw = row & 1023;
                    ((float*)outp)[(size_t)b * (OCN * HWN) + (size_t)col * HWN + hw] = val;
                }
            }
        }
    }
}

// ---------------------------------------------------------------- RNN scan
// 4 slices x 32 batches = 128 WGs (slices of a batch share wg%8 -> same XCD
// under round-robin dispatch). Rounds 3-7: step time invariant to all weight
// residency tricks => the MALL round trip (agent atomics) is the critical
// path (~3300 cyc/step). This round: dual-path handshake.
//   FAST: publisher stores h-words at WORKGROUP scope (plain store, write-
//         through into the shared same-XCD L2); pollers use workgroup-scope
//         atomic CAS (atomics bypass L1 -> no stale lines; no sc1 -> executes
//         at local L2, ~300 cyc instead of ~900 MALL).
//   SLOW: every publish mirrored at AGENT scope (MALL); pollers alternate
//         fast CAS / slow load -> correct under ANY placement (G16), fast
//         when the %8 mapping holds.
// Also: thread = (row, k-quarter); reduction = shfl_xor butterfly in-wave
// (part[] LDS eliminated); h double-buffered in LDS by parity -> ONE
// __syncthreads per step.
__device__ __forceinline__ float dot2acc(u32 w, f16x2 h, float c) {
#if __has_builtin(__builtin_amdgcn_fdot2)
    return __builtin_amdgcn_fdot2(__builtin_bit_cast(f16x2, w), h, c, false);
#else
    f16x2 a = __builtin_bit_cast(f16x2, w);
    return c + (float)a[0] * (float)h[0] + (float)a[1] * (float)h[1];
#endif
}

#define QSTEP(hv, Wq, acc)                                          \
    acc = dot2acc(Wq.x, __builtin_bit_cast(f16x2, hv.x), acc);      \
    acc = dot2acc(Wq.y, __builtin_bit_cast(f16x2, hv.y), acc);      \
    acc = dot2acc(Wq.z, __builtin_bit_cast(f16x2, hv.z), acc);      \
    acc = dot2acc(Wq.w, __builtin_bit_cast(f16x2, hv.w), acc);

__global__ __launch_bounds__(512, 2) void rnn_kernel(const u32* WR,
                                                     f16* __restrict__ xh,
                                                     u64* slow, u64* fast) {
    const int wg = blockIdx.x;
    const int b  = wg & 31;   // batch
    const int s  = wg >> 5;   // slice: rows [128s, 128s+128)
    const int t  = threadIdx.x;
    const int row = t >> 2;   // local row 0..127
    const int kq  = t & 3;    // k-quarter: pairs kq*64 .. +63

    __shared__ __align__(16) u32 hbuf[2][256];   // 512 f16 per parity

    // weight words for (row, kq): 64 u32 -> 16 named uint4 (provenance
    // hidden; WR/slow/fast not restrict so in-loop stores may alias).
    unsigned long long wpa =
        (unsigned long long)(WR + ((size_t)(s * 512 + t) << 6));
    asm volatile("" : "+v"(wpa));
    const uint4* wp = (const uint4*)wpa;
    uint4 W0 = wp[0],  W1 = wp[1],  W2 = wp[2],  W3 = wp[3];
    uint4 W4 = wp[4],  W5 = wp[5],  W6 = wp[6],  W7 = wp[7];
    uint4 W8 = wp[8],  W9 = wp[9],  W10 = wp[10], W11 = wp[11];
    uint4 W12 = wp[12], W13 = wp[13], W14 = wp[14], W15 = wp[15];

    if (t < 256) hbuf[0][t] = 0u;
    __syncthreads();

    f16* xb = xh + (size_t)b * (HWN * RH) + s * 128;  // slice base
    float xnext = 0.f;
    if ((t & 3) == 3) xnext = (float)xb[row];

    u64* cbS = slow + (size_t)b * 256;
    u64* cbF = fast + (size_t)b * 256;

    for (int step = 0; step < HWN; step++) {
        const u32 tag = (u32)(step + 1);
        const size_t pbase = (size_t)(tag & 1) * 8192;
        const u32* hcur = hbuf[step & 1];
        u32* hnext = hbuf[tag & 1];

        // ---- 64 fdot2 over this thread's k-quarter (4 independent chains)
        const uint4* hqb = ((const uint4*)hcur) + kq * 16;
        float a0 = 0.f, a1 = 0.f, a2 = 0.f, a3 = 0.f;
        {
            uint4 h0 = hqb[0],  h1 = hqb[1],  h2 = hqb[2],  h3 = hqb[3];
            QSTEP(h0, W0, a0) QSTEP(h1, W1, a1) QSTEP(h2, W2, a2) QSTEP(h3, W3, a3)
            uint4 h4 = hqb[4],  h5 = hqb[5],  h6 = hqb[6],  h7 = hqb[7];
            QSTEP(h4, W4, a0) QSTEP(h5, W5, a1) QSTEP(h6, W6, a2) QSTEP(h7, W7, a3)
            uint4 h8 = hqb[8],  h9 = hqb[9],  h10 = hqb[10], h11 = hqb[11];
            QSTEP(h8, W8, a0) QSTEP(h9, W9, a1) QSTEP(h10, W10, a2) QSTEP(h11, W11, a3)
            uint4 h12 = hqb[12], h13 = hqb[13], h14 = hqb[14], h15 = hqb[15];
            QSTEP(h12, W12, a0) QSTEP(h13, W13, a1) QSTEP(h14, W14, a2) QSTEP(h15, W15, a3)
        }
        float y = (a0 + a1) + (a2 + a3);
        // butterfly over the 4 k-quarter lanes of this row
        y += __shfl_xor(y, 1, 64);
        y += __shfl_xor(y, 2, 64);

        f16 hf = (f16)0.f;
        float xcur = xnext;
        if ((t & 3) == 3) {
            hf = (f16)tanhf(y + xcur);
            if (step + 1 < HWN) xnext = (float)xb[(size_t)(step + 1) * RH + row];
        }
        u32 hu = (u32)__builtin_bit_cast(unsigned short, hf);
        u32 hlo = (u32)__shfl_up((int)hu, 4, 64);   // lane 8w+7 <- lane 8w+3

        if ((t & 7) == 7) {
            int w = t >> 3;                         // word 0..63: rows 2w,2w+1
            u32 word = hlo | (hu << 16);
            hnext[s * 64 + w] = word;               // own slice into LDS
            ((u32*)(xb + (size_t)step * RH))[w] = word;  // hs output
            u64 v = ((u64)tag << 32) | (u64)word;
            __hip_atomic_store(&cbF[pbase + s * 64 + w], v,
                               __ATOMIC_RELAXED, __HIP_MEMORY_SCOPE_WORKGROUP);
            __hip_atomic_store(&cbS[pbase + s * 64 + w], v,
                               __ATOMIC_RELAXED, __HIP_MEMORY_SCOPE_AGENT);
        }
        // ---- gather 3 partner slices: fast CAS (local L2) + slow fallback
        if (t < 192) {
            int pi = t >> 6;
            int widx = t & 63;
            int p = pi + (pi >= s ? 1 : 0);
            u64* aF = &cbF[pbase + p * 64 + widx];
            u64* aS = &cbS[pbase + p * 64 + widx];
            u64 exp = 0;
            u32 pay;
            int guard = 0;
            for (;;) {
                u64 cur = exp;
                __hip_atomic_compare_exchange_strong(
                    aF, &cur, cur, __ATOMIC_RELAXED, __ATOMIC_RELAXED,
                    __HIP_MEMORY_SCOPE_WORKGROUP);
                if ((u32)(cur >> 32) == tag) { pay = (u32)cur; break; }
                exp = cur;
                u64 vs = __hip_atomic_load(aS, __ATOMIC_RELAXED,
                                           __HIP_MEMORY_SCOPE_AGENT);
                if ((u32)(vs >> 32) == tag) { pay = (u32)vs; break; }
                if (++guard > (1 << 17)) { pay = (u32)vs; break; }
            }
            hnext[p * 64 + widx] = pay;
        }
        __syncthreads();
    }
}

// ------------------------------------------------------------------ launch
extern "C" void kernel_launch(void* const* d_in, const int* in_sizes, int n_in,
                              void* d_out, int out_size, void* d_ws, size_t ws_size,
                              hipStream_t stream) {
    const float* x     = (const float*)d_in[0];
    const float* gamma = (const float*)d_in[1];
    const float* beta  = (const float*)d_in[2];
    const float* w_in  = (const float*)d_in[3];
    const float* b_in  = (const float*)d_in[4];
    const float* w_ih  = (const float*)d_in[5];
    const float* b_ih  = (const float*)d_in[6];
    const float* w_hh  = (const float*)d_in[7];
    const float* b_hh  = (const float*)d_in[8];
    const float* w_out = (const float*)d_in[9];
    const float* b_out = (const float*)d_in[10];

    char* ws = (char*)d_ws;
    float* scale   = (float*)(ws + 0);         //   512 B
    float* shift   = (float*)(ws + 512);       //   512 B
    float* bihh    = (float*)(ws + 1024);      //  2 KB
    f16*   w_in_h  = (f16*)(ws + 4096);        // 64 KB
    f16*   w_ih_h  = (f16*)(ws + 69632);       // 256 KB
    f16*   w_out_h = (f16*)(ws + 331776);      // 128 KB
    u32*   wr      = (u32*)(ws + 462848);      // 512 KB packed W_hh
    u64*   cslow   = (u64*)(ws + 987136);      // 128 KB slow comm (MALL)
    u64*   cfast   = (u64*)(ws + 1118208);     // 128 KB fast comm (local L2)
    f16*   xh      = (f16*)(ws + 1310720);     // 32 MB xgate, overwritten by hs
    f16*   A1      = (f16*)(ws + 34865152);    //  8 MB
    f16*   inp     = (f16*)(ws + 43253760);    // 16 MB (ends 60030976)

    bn_stats_kernel<<<128, 256, 0, stream>>>(x, gamma, beta, scale, shift);
    prep_w_kernel<<<1538, 256, 0, stream>>>(w_in, w_ih, w_out, w_hh, b_ih, b_hh,
                                            w_in_h, w_ih_h, w_out_h, wr, bihh, cslow);
    prep_x_kernel<<<dim3(32, 4, 32), dim3(32, 8), 0, stream>>>(x, scale, shift, A1);
    gemm_kernel<0><<<dim3(128, 4), 256, 0, stream>>>(A1, w_in_h, b_in, (void*)inp, RIN, CC);
    gemm_kernel<1><<<dim3(128, 8), 256, 0, stream>>>(inp, w_ih_h, bihh, (void*)xh, RH, RIN);
    rnn_kernel<<<128, 512, 0, stream>>>(wr, xh, cslow, cfast);
    gemm_kernel<2><<<dim3(128, 2), 256, 0, stream>>>(xh, w_out_h, b_out, d_out, OCN, RH);
}

// Round 9
// 1618.234 us; speedup vs baseline: 1.5100x; 1.5100x over previous
//
#include <hip/hip_runtime.h>
#include <hip/hip_fp16.h>

typedef _Float16 f16;
typedef _Float16 f16x2 __attribute__((ext_vector_type(2)));
typedef _Float16 f16x8 __attribute__((ext_vector_type(8)));
typedef float    f32x4 __attribute__((ext_vector_type(4)));
typedef unsigned int u32;
typedef unsigned long long u64;

#define BN_EPS 1e-5f

static constexpr int BB  = 32;    // batch
static constexpr int CC  = 128;   // channels
static constexpr int HWN = 1024;  // H*W = L
static constexpr int RIN = 256;
static constexpr int RH  = 512;
static constexpr int OCN = 128;

// ---------------------------------------------------------------- BN stats
__global__ void bn_stats_kernel(const float* __restrict__ x,
                                const float* __restrict__ gamma,
                                const float* __restrict__ beta,
                                float* __restrict__ scale,
                                float* __restrict__ shift) {
    int c = blockIdx.x;
    int tid = threadIdx.x;
    float s = 0.f, s2 = 0.f;
    const float* xc = x + (size_t)c * HWN;
    for (int idx = tid; idx < BB * HWN; idx += 256) {
        int b = idx >> 10, hw = idx & 1023;
        float v = xc[(size_t)b * (CC * HWN) + hw];
        s += v; s2 += v * v;
    }
    for (int off = 32; off > 0; off >>= 1) {
        s  += __shfl_down(s, off, 64);
        s2 += __shfl_down(s2, off, 64);
    }
    __shared__ float ls[4], ls2[4];
    int wv = tid >> 6, ln = tid & 63;
    if (ln == 0) { ls[wv] = s; ls2[wv] = s2; }
    __syncthreads();
    if (tid == 0) {
        float ts  = ls[0] + ls[1] + ls[2] + ls[3];
        float ts2 = ls2[0] + ls2[1] + ls2[2] + ls2[3];
        const float inv_n = 1.0f / (BB * HWN);
        float mean = ts * inv_n;
        float var  = ts2 * inv_n - mean * mean;
        float rstd = rsqrtf(var + BN_EPS);
        float sc = gamma[c] * rstd;
        scale[c] = sc;
        shift[c] = beta[c] - mean * sc;
    }
}

// ------------------------------------------- normalize + transpose -> A1 f16
__global__ void prep_x_kernel(const float* __restrict__ x,
                              const float* __restrict__ scale,
                              const float* __restrict__ shift,
                              f16* __restrict__ A1) {
    __shared__ float tile[32][33];
    int tx = threadIdx.x, ty = threadIdx.y;  // 32 x 8
    int hb = blockIdx.x, cb = blockIdx.y, b = blockIdx.z;
    #pragma unroll
    for (int k = 0; k < 4; k++) {
        int c  = cb * 32 + ty + 8 * k;
        int hw = hb * 32 + tx;
        tile[ty + 8 * k][tx] = x[(size_t)b * (CC * HWN) + (size_t)c * HWN + hw];
    }
    __syncthreads();
    #pragma unroll
    for (int k = 0; k < 4; k++) {
        int hw = hb * 32 + ty + 8 * k;
        int c  = cb * 32 + tx;
        float v = tile[tx][ty + 8 * k];
        A1[(size_t)(b * HWN + hw) * CC + c] = (f16)(v * scale[c] + shift[c]);
    }
}

// ------------------------------------------------------------ weight prep
// round-7 packing: word idx -> (slice s, thread t, reg k); reg k = r*16+n
__global__ void prep_w_kernel(const float* __restrict__ w_in,
                              const float* __restrict__ w_ih,
                              const float* __restrict__ w_out,
                              const float* __restrict__ w_hh,
                              const float* __restrict__ b_ih,
                              const float* __restrict__ b_hh,
                              f16* __restrict__ w_in_h,
                              f16* __restrict__ w_ih_h,
                              f16* __restrict__ w_out_h,
                              u32* __restrict__ wr,
                              float* __restrict__ bihh,
                              u64* __restrict__ comm) {
    int idx = blockIdx.x * 256 + threadIdx.x;
    if (idx < 32768) { w_in_h[idx] = (f16)w_in[idx]; return; }
    idx -= 32768;
    if (idx < 131072) { w_ih_h[idx] = (f16)w_ih[idx]; return; }
    idx -= 131072;
    if (idx < 65536) { w_out_h[idx] = (f16)w_out[idx]; return; }
    idx -= 65536;
    if (idx < 131072) {
        int s = idx >> 15, rem = idx & 32767;
        int t = rem >> 6, k = rem & 63;
        int r = k >> 4, n = k & 15;
        int jg = t & 31, sl = t >> 5;
        int j  = s * 128 + 4 * jg + r;       // output row
        int i2 = sl * 16 + n;                // h-pair index
        f16 lo = (f16)w_hh[(size_t)j * 512 + 2 * i2];
        f16 hi = (f16)w_hh[(size_t)j * 512 + 2 * i2 + 1];
        wr[idx] = (u32)__builtin_bit_cast(unsigned short, lo) |
                  ((u32)__builtin_bit_cast(unsigned short, hi) << 16);
        return;
    }
    idx -= 131072;
    if (idx < 512) { bihh[idx] = b_ih[idx] + b_hh[idx]; return; }
    idx -= 512;
    if (idx < 32768) comm[idx] = 0ULL;   // zero BOTH slow and fast buffers
}

// ------------------------------------------------------------- MFMA GEMM
template <int MODE>
__global__ void gemm_kernel(const f16* __restrict__ A,
                            const f16* __restrict__ W,
                            const float* __restrict__ bias,
                            void* __restrict__ outp,
                            int N, int K) {
    int wave = threadIdx.x >> 6;
    int lane = threadIdx.x & 63;
    int q = lane >> 4, r = lane & 15;
    int bm = blockIdx.x * 256 + wave * 64;
    int bn = blockIdx.y * 64;

    f32x4 acc[4][4];
    #pragma unroll
    for (int i = 0; i < 4; i++)
        #pragma unroll
        for (int j = 0; j < 4; j++)
            acc[i][j] = (f32x4){0.f, 0.f, 0.f, 0.f};

    const f16* Ap = A + (size_t)(bm + r) * K + 8 * q;
    const f16* Wp = W + (size_t)(bn + r) * K + 8 * q;

    for (int k = 0; k < K; k += 32) {
        f16x8 av[4], bv[4];
        #pragma unroll
        for (int i = 0; i < 4; i++)
            av[i] = *(const f16x8*)(Ap + (size_t)(16 * i) * K + k);
        #pragma unroll
        for (int i = 0; i < 4; i++)
            bv[i] = *(const f16x8*)(Wp + (size_t)(16 * i) * K + k);
        #pragma unroll
        for (int mi = 0; mi < 4; mi++)
            #pragma unroll
            for (int ni = 0; ni < 4; ni++)
                acc[mi][ni] = __builtin_amdgcn_mfma_f32_16x16x32_f16(
                    av[mi], bv[ni], acc[mi][ni], 0, 0, 0);
    }

    #pragma unroll
    for (int mi = 0; mi < 4; mi++) {
        #pragma unroll
        for (int ni = 0; ni < 4; ni++) {
            int col = bn + 16 * ni + r;
            float bval = bias[col];
            #pragma unroll
            for (int i = 0; i < 4; i++) {
                int row = bm + 16 * mi + 4 * q + i;
                float val = acc[mi][ni][i] + bval;
                if (MODE == 0) {
                    val = val - tanhf(val);
                    ((f16*)outp)[(size_t)row * N + col] = (f16)val;
                } else if (MODE == 1) {
                    ((f16*)outp)[(size_t)row * N + col] = (f16)val;
                } else {
                    int b = row >> 10, hw = row & 1023;
                    ((float*)outp)[(size_t)b * (OCN * HWN) + (size_t)col * HWN + hw] = val;
                }
            }
        }
    }
}

// ---------------------------------------------------------------- RNN scan
// Round-7 body (known 1407us, ZERO LDS conflicts) with ONLY the handshake
// changed. Round-8 lessons: CAS polling = RMW write traffic (556 MB -> fabric
// flood); 256B-stride LDS reads = 4-way bank conflicts (2e8). Both reverted.
// Handshake now:
//   publish: workgroup-scope store (plain global store, write-through vL1
//            -> lands in the local XCD L2) + agent-scope store (MALL,
//            correctness under any WG->XCD placement).
//   poll:    read-only `sc0` load via asm (bypasses the poller's stale L1,
//            reads the same-XCD L2, ~250 cyc) alternated with the agent-
//            scope load (MALL fallback). Loads only -> no write traffic.
// Slices of a batch share wg%8 -> same XCD under round-robin dispatch; if
// that heuristic fails we degrade to round-7 latency, never to wrongness.
__device__ __forceinline__ float dot2acc(u32 w, f16x2 h, float c) {
#if __has_builtin(__builtin_amdgcn_fdot2)
    return __builtin_amdgcn_fdot2(__builtin_bit_cast(f16x2, w), h, c, false);
#else
    f16x2 a = __builtin_bit_cast(f16x2, w);
    return c + (float)a[0] * (float)h[0] + (float)a[1] * (float)h[1];
#endif
}

#define ROW16(acc, WA, WB, WC, WD)                                  \
    acc = dot2acc(WA.x, H0,  acc); acc = dot2acc(WA.y, H1,  acc);   \
    acc = dot2acc(WA.z, H2,  acc); acc = dot2acc(WA.w, H3,  acc);   \
    acc = dot2acc(WB.x, H4,  acc); acc = dot2acc(WB.y, H5,  acc);   \
    acc = dot2acc(WB.z, H6,  acc); acc = dot2acc(WB.w, H7,  acc);   \
    acc = dot2acc(WC.x, H8,  acc); acc = dot2acc(WC.y, H9,  acc);   \
    acc = dot2acc(WC.z, H10, acc); acc = dot2acc(WC.w, H11, acc);   \
    acc = dot2acc(WD.x, H12, acc); acc = dot2acc(WD.y, H13, acc);   \
    acc = dot2acc(WD.z, H14, acc); acc = dot2acc(WD.w, H15, acc)

__global__ __launch_bounds__(512, 2) void rnn_kernel(const u32* WR,
                                                     f16* __restrict__ xh,
                                                     u64* slow, u64* fast) {
    const int wg = blockIdx.x;
    const int b  = wg & 31;   // batch
    const int s  = wg >> 5;   // slice: rows [128s, 128s+128)
    const int t  = threadIdx.x;
    const int jg = t & 31;    // 4 rows: 128s + 4jg .. +3
    const int sl = t >> 5;    // 16 h-pair slices of 16 pairs

    __shared__ __align__(16) f16 hbuf[512];
    __shared__ float part[16][128];

    // weight words -> 16 named uint4 (provenance hidden; non-restrict
    // pointers so in-loop stores may alias -> no remat into the loop).
    unsigned long long wpa =
        (unsigned long long)(WR + ((size_t)(s * 512 + t) << 6));
    asm volatile("" : "+v"(wpa));
    const uint4* wp = (const uint4*)wpa;
    uint4 W0 = wp[0],  W1 = wp[1],  W2 = wp[2],  W3 = wp[3];
    uint4 W4 = wp[4],  W5 = wp[5],  W6 = wp[6],  W7 = wp[7];
    uint4 W8 = wp[8],  W9 = wp[9],  W10 = wp[10], W11 = wp[11];
    uint4 W12 = wp[12], W13 = wp[13], W14 = wp[14], W15 = wp[15];

    if (t < 256) ((u32*)hbuf)[t] = 0u;
    __syncthreads();

    f16* xb = xh + (size_t)b * (HWN * RH) + s * 128;  // + step*RH + t
    float xnext = 0.f;
    if (t < 128) xnext = (float)xb[t];

    u64* cbS = slow + (size_t)b * 256;
    u64* cbF = fast + (size_t)b * 256;
    const uint4* hq = (const uint4*)hbuf;

    for (int step = 0; step < HWN; step++) {
        float xcur = xnext;
        if (t < 128 && step + 1 < HWN)
            xnext = (float)xb[(size_t)(step + 1) * RH + t];

        // ---- partial y for 4 rows over this thread's 16 h-pairs
        uint4 q0 = hq[sl*4+0], q1 = hq[sl*4+1], q2 = hq[sl*4+2], q3 = hq[sl*4+3];
        f16x2 H0  = __builtin_bit_cast(f16x2, q0.x), H1  = __builtin_bit_cast(f16x2, q0.y);
        f16x2 H2  = __builtin_bit_cast(f16x2, q0.z), H3  = __builtin_bit_cast(f16x2, q0.w);
        f16x2 H4  = __builtin_bit_cast(f16x2, q1.x), H5  = __builtin_bit_cast(f16x2, q1.y);
        f16x2 H6  = __builtin_bit_cast(f16x2, q1.z), H7  = __builtin_bit_cast(f16x2, q1.w);
        f16x2 H8  = __builtin_bit_cast(f16x2, q2.x), H9  = __builtin_bit_cast(f16x2, q2.y);
        f16x2 H10 = __builtin_bit_cast(f16x2, q2.z), H11 = __builtin_bit_cast(f16x2, q2.w);
        f16x2 H12 = __builtin_bit_cast(f16x2, q3.x), H13 = __builtin_bit_cast(f16x2, q3.y);
        f16x2 H14 = __builtin_bit_cast(f16x2, q3.z), H15 = __builtin_bit_cast(f16x2, q3.w);
        float a0 = 0.f, a1 = 0.f, a2 = 0.f, a3 = 0.f;
        ROW16(a0, W0,  W1,  W2,  W3);
        ROW16(a1, W4,  W5,  W6,  W7);
        ROW16(a2, W8,  W9,  W10, W11);
        ROW16(a3, W12, W13, W14, W15);
        *(f32x4*)&part[sl][4 * jg] = (f32x4){a0, a1, a2, a3};
        __syncthreads();

        const u32 tag = (u32)(step + 1);
        const size_t pbase = (size_t)(tag & 1) * 8192;

        // ---- waves 4-6: poll for the 3 partner slices
        if (t >= 256 && t < 448) {
            int pi = (t - 256) >> 6;
            int widx = t & 63;
            int p = pi + (pi >= s ? 1 : 0);
            const u64* aF = &cbF[pbase + p * 64 + widx];
            u64* aS = &cbS[pbase + p * 64 + widx];
            u64 v;
            int guard = 0;
            for (;;) {
                // fast: same-XCD L2 read (bypass own L1 via sc0), read-only
                asm volatile("global_load_dwordx2 %0, %1, off sc0\n\t"
                             "s_waitcnt vmcnt(0)"
                             : "=&v"(v) : "v"(aF) : "memory");
                if ((u32)(v >> 32) == tag) break;
                // slow: MALL (coherent under any WG placement)
                v = __hip_atomic_load(aS, __ATOMIC_RELAXED,
                                      __HIP_MEMORY_SCOPE_AGENT);
                if ((u32)(v >> 32) == tag) break;
                if (++guard > (1 << 17)) break;
            }
            ((u32*)hbuf)[p * 64 + widx] = (u32)v;
        }
        // ---- waves 0-1: finalize own 128 rows, publish ASAP
        if (t < 128) {
            float y = xcur;
            #pragma unroll
            for (int k = 0; k < 16; k++) y += part[k][t];
            float h = tanhf(y);
            f16 hf = (f16)h;
            u32 hu = (u32)__builtin_bit_cast(unsigned short, hf);
            u32 other = (u32)__shfl_down((int)hu, 1, 64);
            if ((t & 1) == 0) {
                u64 v = ((u64)tag << 32) | (u64)(hu | (other << 16));
                // fast: plain write-through -> lands in local XCD L2
                __hip_atomic_store(&cbF[pbase + s * 64 + (t >> 1)], v,
                                   __ATOMIC_RELAXED, __HIP_MEMORY_SCOPE_WORKGROUP);
                // slow: MALL mirror for cross-XCD correctness
                __hip_atomic_store(&cbS[pbase + s * 64 + (t >> 1)], v,
                                   __ATOMIC_RELAXED, __HIP_MEMORY_SCOPE_AGENT);
            }
            hbuf[s * 128 + t] = hf;                 // own slice into local h
            xb[(size_t)step * RH + t] = hf;         // hs output (in place)
        }
        __syncthreads();
    }
}

// ------------------------------------------------------------------ launch
extern "C" void kernel_launch(void* const* d_in, const int* in_sizes, int n_in,
                              void* d_out, int out_size, void* d_ws, size_t ws_size,
                              hipStream_t stream) {
    const float* x     = (const float*)d_in[0];
    const float* gamma = (const float*)d_in[1];
    const float* beta  = (const float*)d_in[2];
    const float* w_in  = (const float*)d_in[3];
    const float* b_in  = (const float*)d_in[4];
    const float* w_ih  = (const float*)d_in[5];
    const float* b_ih  = (const float*)d_in[6];
    const float* w_hh  = (const float*)d_in[7];
    const float* b_hh  = (const float*)d_in[8];
    const float* w_out = (const float*)d_in[9];
    const float* b_out = (const float*)d_in[10];

    char* ws = (char*)d_ws;
    float* scale   = (float*)(ws + 0);         //   512 B
    float* shift   = (float*)(ws + 512);       //   512 B
    float* bihh    = (float*)(ws + 1024);      //  2 KB
    f16*   w_in_h  = (f16*)(ws + 4096);        // 64 KB
    f16*   w_ih_h  = (f16*)(ws + 69632);       // 256 KB
    f16*   w_out_h = (f16*)(ws + 331776);      // 128 KB
    u32*   wr      = (u32*)(ws + 462848);      // 512 KB packed W_hh
    u64*   cslow   = (u64*)(ws + 987136);      // 128 KB slow comm (MALL)
    u64*   cfast   = (u64*)(ws + 1118208);     // 128 KB fast comm (local L2)
    f16*   xh      = (f16*)(ws + 1310720);     // 32 MB xgate, overwritten by hs
    f16*   A1      = (f16*)(ws + 34865152);    //  8 MB
    f16*   inp     = (f16*)(ws + 43253760);    // 16 MB (ends 60030976)

    bn_stats_kernel<<<128, 256, 0, stream>>>(x, gamma, beta, scale, shift);
    prep_w_kernel<<<1538, 256, 0, stream>>>(w_in, w_ih, w_out, w_hh, b_ih, b_hh,
                                            w_in_h, w_ih_h, w_out_h, wr, bihh, cslow);
    prep_x_kernel<<<dim3(32, 4, 32), dim3(32, 8), 0, stream>>>(x, scale, shift, A1);
    gemm_kernel<0><<<dim3(128, 4), 256, 0, stream>>>(A1, w_in_h, b_in, (void*)inp, RIN, CC);
    gemm_kernel<1><<<dim3(128, 8), 256, 0, stream>>>(inp, w_ih_h, bihh, (void*)xh, RH, RIN);
    rnn_kernel<<<128, 512, 0, stream>>>(wr, xh, cslow, cfast);
    gemm_kernel<2><<<dim3(128, 2), 256, 0, stream>>>(xh, w_out_h, b_out, d_out, OCN, RH);
}